// Round 2
// baseline (377.400 us; speedup 1.0000x reference)
//
#include <hip/hip_runtime.h>
#include <hip/hip_bf16.h>
#include <stdint.h>

#define DIMK 256
#define DIMV 384
#define NSEQ 1024
#define NHEAD 6

typedef __attribute__((ext_vector_type(8))) short short8;
typedef __attribute__((ext_vector_type(4))) float floatx4;

__device__ __forceinline__ unsigned short f2b(float f){
  unsigned int x = __float_as_uint(f);
  return (unsigned short)((x + 0x7fffu + ((x >> 16) & 1u)) >> 16);
}
__device__ __forceinline__ unsigned int pack2(float a, float b){
  return (unsigned int)f2b(a) | ((unsigned int)f2b(b) << 16);
}

// transpose + convert: W [256][384] f32 -> Wt [384][256] bf16 (both weights)
__global__ void conv_w_kernel(const float* __restrict__ WQ, const float* __restrict__ WK,
                              unsigned short* __restrict__ wqt, unsigned short* __restrict__ wkt){
  int i = blockIdx.x * 256 + threadIdx.x;      // 0 .. 196607
  const float* W; unsigned short* O; int idx;
  if (i < 98304){ W = WQ; O = wqt; idx = i; }
  else          { W = WK; O = wkt; idx = i - 98304; }
  int n = idx >> 8;          // 0..383
  int k = idx & 255;         // 0..255
  O[idx] = f2b(W[(size_t)k * 384 + n]);
}

// Y[M=8192][384] = bf16(X[8192][256]) @ bf16(W)[256][384] + bias   (f32 out)
__global__ __launch_bounds__(256) void proj_kernel(const float* __restrict__ X,
    const unsigned short* __restrict__ Wt,   // [384][256] bf16 (pre-transposed)
    const float* __restrict__ bias,
    float* __restrict__ Y)
{
  __shared__ uint4 lA[512];       // [kc 0..7][row 0..63]
  __shared__ uint4 lB[864];       // [n 0..95][kc 0..8 (pad)]
  int t = threadIdx.x;
  int lane = t & 63, wave = t >> 6;
  int wm = wave >> 1, wn = wave & 1;
  int rb = blockIdx.x * 64;
  int nb = blockIdx.y * 96;
  floatx4 acc[2][3];
  #pragma unroll
  for (int mi = 0; mi < 2; ++mi)
    #pragma unroll
    for (int ni = 0; ni < 3; ++ni) acc[mi][ni] = (floatx4){0.f, 0.f, 0.f, 0.f};

  for (int it = 0; it < 4; ++it){
    int k0 = it * 64;
    #pragma unroll
    for (int i = 0; i < 2; ++i){
      int c = t + i * 256;
      int kc = c >> 6, row = c & 63;
      const float* src = X + (size_t)(rb + row) * DIMK + k0 + kc * 8;
      float4 f0 = *(const float4*)src;
      float4 f1 = *(const float4*)(src + 4);
      uint4 w;
      w.x = pack2(f0.x, f0.y); w.y = pack2(f0.z, f0.w);
      w.z = pack2(f1.x, f1.y); w.w = pack2(f1.z, f1.w);
      lA[c] = w;
    }
    #pragma unroll
    for (int i = 0; i < 3; ++i){
      int c = t + i * 256;
      int n = c >> 3, kc = c & 7;
      uint4 v = *(const uint4*)(Wt + (size_t)(nb + n) * DIMK + k0 + kc * 8);
      lB[n * 9 + kc] = v;
    }
    __syncthreads();
    #pragma unroll
    for (int kk = 0; kk < 2; ++kk){
      int kc  = kk * 4 + (lane >> 4);
      int r16 = lane & 15;
      short8 af[2], bf[3];
      #pragma unroll
      for (int mi = 0; mi < 2; ++mi)
        af[mi] = *(const short8*)&lA[kc * 64 + wm * 32 + mi * 16 + r16];
      #pragma unroll
      for (int ni = 0; ni < 3; ++ni)
        bf[ni] = *(const short8*)&lB[(wn * 48 + ni * 16 + r16) * 9 + kc];
      #pragma unroll
      for (int mi = 0; mi < 2; ++mi)
        #pragma unroll
        for (int ni = 0; ni < 3; ++ni)
          acc[mi][ni] = __builtin_amdgcn_mfma_f32_16x16x32_bf16(af[mi], bf[ni], acc[mi][ni], 0, 0, 0);
    }
    __syncthreads();
  }
  int r16 = lane & 15, rq = lane >> 4;
  #pragma unroll
  for (int ni = 0; ni < 3; ++ni){
    int col = nb + wn * 48 + ni * 16 + r16;
    float bv = bias[col];
    #pragma unroll
    for (int mi = 0; mi < 2; ++mi){
      #pragma unroll
      for (int q = 0; q < 4; ++q){
        int row = rb + wm * 32 + mi * 16 + rq * 4 + q;
        Y[(size_t)row * DIMV + col] = acc[mi][ni][q] + bv;
      }
    }
  }
}

__device__ __forceinline__ float dot64(const float4* __restrict__ kp, const float4* __restrict__ qv){
  float z0 = 0.f, z1 = 0.f;
  #pragma unroll
  for (int c = 0; c < 8; ++c){
    float4 kv0 = kp[2*c];
    float4 kv1 = kp[2*c+1];
    float4 q0 = qv[2*c];
    float4 q1 = qv[2*c+1];
    z0 += kv0.x*q0.x + kv0.y*q0.y + kv0.z*q0.z + kv0.w*q0.w;
    z1 += kv1.x*q1.x + kv1.y*q1.y + kv1.z*q1.z + kv1.w*q1.w;
  }
  return z0 + z1;
}

// One workgroup per (b,n) row; 6 waves = 1 per head.
// Lane-parallel over masked indices: lane j owns idxs[j], computes its own
// 64-dim dot (16 float4 gathers + q broadcast from LDS). Sparsemax via
// register bisection. Output staged in LDS, written coalesced.
__global__ __launch_bounds__(384) void attn_kernel(const float* __restrict__ qb,
    const float* __restrict__ kb, const float* __restrict__ A, float* __restrict__ out)
{
  __shared__ int   idxs[1024];
  __shared__ float qsh[NHEAD][64];
  __shared__ float obuf[NHEAD][1024];
  __shared__ int   Msh;
  int r = blockIdx.x;            // b*1024 + n
  int b = r >> 10;
  int t = threadIdx.x;
  int lane = t & 63, wave = t >> 6;

  qsh[wave][lane] = qb[(size_t)r * DIMV + wave * 64 + lane];

  if (wave == 0){
    const float4* arow = (const float4*)(A + (size_t)r * NSEQ);
    float4 av[4];
    #pragma unroll
    for (int c = 0; c < 4; ++c) av[c] = arow[c * 64 + lane];
    int base = 0;
    #pragma unroll
    for (int c = 0; c < 4; ++c){
      #pragma unroll
      for (int e = 0; e < 4; ++e){
        float a = (e==0)?av[c].x:(e==1)?av[c].y:(e==2)?av[c].z:av[c].w;
        bool on = a > 0.5f;
        unsigned long long m = __ballot(on);
        int pre = __popcll(m & ((1ull << lane) - 1ull));
        if (on) idxs[base + pre] = (c * 64 + lane) * 4 + e;   // order-free compaction
        base += __popcll(m);
      }
    }
    if (lane == 0) Msh = base;
  }
  __syncthreads();
  int M = Msh;

  float* ob = obuf[wave];
  // zero output staging (per-wave private; same-wave LDS ops are in-order)
  float4 z4 = make_float4(0.f, 0.f, 0.f, 0.f);
  #pragma unroll
  for (int u = 0; u < 4; ++u) ((float4*)ob)[u * 64 + lane] = z4;

  const float* kbh = kb + (size_t)b * NSEQ * DIMV + wave * 64;
  const float4* qv = (const float4*)qsh[wave];
  const float scale = 0.05103103630798288f;    // 1/sqrt(384)

  if (M <= 64){
    // ---- common path: one index per lane, all in registers ----
    float z = -1e30f; int myidx = -1;
    if (lane < M){
      myidx = idxs[lane];
      z = dot64((const float4*)(kbh + (size_t)myidx * DIMV), qv) * scale;
    }
    float maxv = z;
    #pragma unroll
    for (int o = 1; o < 64; o <<= 1) maxv = fmaxf(maxv, __shfl_xor(maxv, o));
    float lo = maxv - 1.0f, hi = maxv;
    #pragma unroll 1
    for (int bi = 0; bi < 28; ++bi){
      float mid = 0.5f * (lo + hi);
      float s = fmaxf(z - mid, 0.f);            // inactive lanes: z=-1e30 -> 0
      #pragma unroll
      for (int o = 1; o < 64; o <<= 1) s += __shfl_xor(s, o);
      if (s >= 1.f) lo = mid; else hi = mid;
    }
    float ssum = (z > lo) ? z : 0.f;
    float cntf = (z > lo) ? 1.f : 0.f;
    #pragma unroll
    for (int o = 1; o < 64; o <<= 1){ ssum += __shfl_xor(ssum, o); cntf += __shfl_xor(cntf, o); }
    float tau = (ssum - 1.0f) / cntf;
    float p = z - tau;
    if (lane < M && p > 0.f) ob[myidx] = p;
  } else {
    // ---- fallback: up to 1024 indices, 16 chunks, static register indexing ----
    float zs[16]; int ids[16];
    float maxv = -1e30f;
    #pragma unroll
    for (int c = 0; c < 16; ++c){
      zs[c] = -1e30f; ids[c] = -1;
      if ((c << 6) < M){                         // wave-uniform guard
        int jj = (c << 6) + lane;
        if (jj < M){
          int idx = idxs[jj]; ids[c] = idx;
          zs[c] = dot64((const float4*)(kbh + (size_t)idx * DIMV), qv) * scale;
        }
        maxv = fmaxf(maxv, zs[c]);
      }
    }
    #pragma unroll
    for (int o = 1; o < 64; o <<= 1) maxv = fmaxf(maxv, __shfl_xor(maxv, o));
    float lo = maxv - 1.0f, hi = maxv;
    #pragma unroll 1
    for (int bi = 0; bi < 28; ++bi){
      float mid = 0.5f * (lo + hi);
      float s = 0.f;
      #pragma unroll
      for (int c = 0; c < 16; ++c)
        if ((c << 6) < M) s += fmaxf(zs[c] - mid, 0.f);
      #pragma unroll
      for (int o = 1; o < 64; o <<= 1) s += __shfl_xor(s, o);
      if (s >= 1.f) lo = mid; else hi = mid;
    }
    float ssum = 0.f, cntf = 0.f;
    #pragma unroll
    for (int c = 0; c < 16; ++c){
      if ((c << 6) < M && zs[c] > lo){ ssum += zs[c]; cntf += 1.f; }
    }
    #pragma unroll
    for (int o = 1; o < 64; o <<= 1){ ssum += __shfl_xor(ssum, o); cntf += __shfl_xor(cntf, o); }
    float tau = (ssum - 1.0f) / cntf;
    #pragma unroll
    for (int c = 0; c < 16; ++c){
      if ((c << 6) < M){
        float p = zs[c] - tau;
        if (ids[c] >= 0 && p > 0.f) ob[ids[c]] = p;
      }
    }
  }

  // coalesced write-out of the staged row (same-wave LDS ordering guarantees
  // zeros -> scatter -> read sequence is respected)
  float* orow = out + (size_t)r * (NHEAD * NSEQ) + wave * NSEQ;
  #pragma unroll
  for (int u = 0; u < 4; ++u){
    float4 v = ((const float4*)ob)[u * 64 + lane];
    ((float4*)orow)[u * 64 + lane] = v;
  }
}

extern "C" void kernel_launch(void* const* d_in, const int* in_sizes, int n_in,
                              void* d_out, int out_size, void* d_ws, size_t ws_size,
                              hipStream_t stream) {
  const float* Q  = (const float*)d_in[0];
  const float* V  = (const float*)d_in[1];
  const float* A  = (const float*)d_in[2];
  const float* WQ = (const float*)d_in[3];
  const float* bQ = (const float*)d_in[4];
  const float* WK = (const float*)d_in[5];
  const float* bK = (const float*)d_in[6];
  float* out = (float*)d_out;

  char* ws = (char*)d_ws;
  const size_t QK_BYTES = (size_t)8192 * 384 * 4;
  float* qbuf = (float*)ws;
  float* kbuf = (float*)(ws + QK_BYTES);
  unsigned short* wqt = (unsigned short*)(ws + 2 * QK_BYTES);
  unsigned short* wkt = wqt + 98304;
  (void)in_sizes; (void)n_in; (void)out_size; (void)ws_size;

  conv_w_kernel<<<768, 256, 0, stream>>>(WQ, WK, wqt, wkt);
  proj_kernel<<<dim3(128, 4), 256, 0, stream>>>(Q, wqt, bQ, qbuf);
  proj_kernel<<<dim3(128, 4), 256, 0, stream>>>(V, wkt, bK, kbuf);
  attn_kernel<<<8192, 384, 0, stream>>>(qbuf, kbuf, A, out);
}

// Round 3
// 211.758 us; speedup vs baseline: 1.7822x; 1.7822x over previous
//
#include <hip/hip_runtime.h>
#include <hip/hip_bf16.h>
#include <stdint.h>

#define DIMK 256
#define DIMV 384
#define NSEQ 1024
#define NHEAD 6

typedef __attribute__((ext_vector_type(8))) short short8;
typedef __attribute__((ext_vector_type(4))) float floatx4;

__device__ __forceinline__ unsigned short f2b(float f){
  unsigned int x = __float_as_uint(f);
  return (unsigned short)((x + 0x7fffu + ((x >> 16) & 1u)) >> 16);
}
__device__ __forceinline__ unsigned int pack2(float a, float b){
  return (unsigned int)f2b(a) | ((unsigned int)f2b(b) << 16);
}

// transpose + convert: W [256][384] f32 -> Wt [384][256] bf16 (both weights)
__global__ void conv_w_kernel(const float* __restrict__ WQ, const float* __restrict__ WK,
                              unsigned short* __restrict__ wqt, unsigned short* __restrict__ wkt){
  int i = blockIdx.x * 256 + threadIdx.x;      // 0 .. 196607
  const float* W; unsigned short* O; int idx;
  if (i < 98304){ W = WQ; O = wqt; idx = i; }
  else          { W = WK; O = wkt; idx = i - 98304; }
  int n = idx >> 8;          // 0..383
  int k = idx & 255;         // 0..255
  O[idx] = f2b(W[(size_t)k * 384 + n]);
}

// Y[M=8192][384] = bf16(X[8192][256]) @ bf16(W)[256][384] + bias   (f32 out)
__global__ __launch_bounds__(256) void proj_kernel(const float* __restrict__ X,
    const unsigned short* __restrict__ Wt,   // [384][256] bf16 (pre-transposed)
    const float* __restrict__ bias,
    float* __restrict__ Y)
{
  __shared__ uint4 lA[512];       // [kc 0..7][row 0..63]
  __shared__ uint4 lB[864];       // [n 0..95][kc 0..8 (pad)]
  int t = threadIdx.x;
  int lane = t & 63, wave = t >> 6;
  int wm = wave >> 1, wn = wave & 1;
  int rb = blockIdx.x * 64;
  int nb = blockIdx.y * 96;
  floatx4 acc[2][3];
  #pragma unroll
  for (int mi = 0; mi < 2; ++mi)
    #pragma unroll
    for (int ni = 0; ni < 3; ++ni) acc[mi][ni] = (floatx4){0.f, 0.f, 0.f, 0.f};

  for (int it = 0; it < 4; ++it){
    int k0 = it * 64;
    #pragma unroll
    for (int i = 0; i < 2; ++i){
      int c = t + i * 256;
      int kc = c >> 6, row = c & 63;
      const float* src = X + (size_t)(rb + row) * DIMK + k0 + kc * 8;
      float4 f0 = *(const float4*)src;
      float4 f1 = *(const float4*)(src + 4);
      uint4 w;
      w.x = pack2(f0.x, f0.y); w.y = pack2(f0.z, f0.w);
      w.z = pack2(f1.x, f1.y); w.w = pack2(f1.z, f1.w);
      lA[c] = w;
    }
    #pragma unroll
    for (int i = 0; i < 3; ++i){
      int c = t + i * 256;
      int n = c >> 3, kc = c & 7;
      uint4 v = *(const uint4*)(Wt + (size_t)(nb + n) * DIMK + k0 + kc * 8);
      lB[n * 9 + kc] = v;
    }
    __syncthreads();
    #pragma unroll
    for (int kk = 0; kk < 2; ++kk){
      int kc  = kk * 4 + (lane >> 4);
      int r16 = lane & 15;
      short8 af[2], bf[3];
      #pragma unroll
      for (int mi = 0; mi < 2; ++mi)
        af[mi] = *(const short8*)&lA[kc * 64 + wm * 32 + mi * 16 + r16];
      #pragma unroll
      for (int ni = 0; ni < 3; ++ni)
        bf[ni] = *(const short8*)&lB[(wn * 48 + ni * 16 + r16) * 9 + kc];
      #pragma unroll
      for (int mi = 0; mi < 2; ++mi)
        #pragma unroll
        for (int ni = 0; ni < 3; ++ni)
          acc[mi][ni] = __builtin_amdgcn_mfma_f32_16x16x32_bf16(af[mi], bf[ni], acc[mi][ni], 0, 0, 0);
    }
    __syncthreads();
  }
  int r16 = lane & 15, rq = lane >> 4;
  #pragma unroll
  for (int ni = 0; ni < 3; ++ni){
    int col = nb + wn * 48 + ni * 16 + r16;
    float bv = bias[col];
    #pragma unroll
    for (int mi = 0; mi < 2; ++mi){
      #pragma unroll
      for (int q = 0; q < 4; ++q){
        int row = rb + wm * 32 + mi * 16 + rq * 4 + q;
        Y[(size_t)row * DIMV + col] = acc[mi][ni][q] + bv;
      }
    }
  }
}

__device__ __forceinline__ float dot64(const float4* __restrict__ kp, const float4* __restrict__ qv){
  float z = 0.f;
  #pragma unroll
  for (int c = 0; c < 16; ++c){
    float4 kv = kp[c];
    float4 q  = qv[c];
    z += kv.x*q.x + kv.y*q.y + kv.z*q.z + kv.w*q.w;
  }
  return z;
}

__device__ __forceinline__ void red2(float& s, float& n){
  #pragma unroll
  for (int o = 1; o < 64; o <<= 1){ s += __shfl_xor(s, o); n += __shfl_xor(n, o); }
}

// One workgroup per (b,n) row; 6 fully independent waves = 1 per head.
// NO barriers: each wave loads the (L1-hot) A row, compacts its own index
// list, lane-parallel dots, Michelot sparsemax in registers, LDS-staged
// coalesced output.
__global__ __launch_bounds__(384) void attn_kernel(const float* __restrict__ qb,
    const float* __restrict__ kb, const float* __restrict__ A, float* __restrict__ out)
{
  __shared__ float obuf[NHEAD][1024];
  __shared__ int   idxw[NHEAD][128];
  __shared__ float qsh[NHEAD][64];

  int bid = blockIdx.x;
  int r = ((bid & 7) << 10) | (bid >> 3);      // XCD swizzle: XCD x owns batch x
  int b = r >> 10;
  int t = threadIdx.x;
  int lane = t & 63, wave = t >> 6;

  // q segment into this wave's LDS slot (same-wave, no barrier needed)
  qsh[wave][lane] = qb[(size_t)r * DIMV + wave * 64 + lane];

  // A-row ballot compaction (per wave; A row is L1-resident after first wave)
  const float4* arow = (const float4*)(A + (size_t)r * NSEQ);
  float4 av[4];
  #pragma unroll
  for (int c = 0; c < 4; ++c) av[c] = arow[c * 64 + lane];
  unsigned long long lmask = (1ull << lane) - 1ull;
  int base = 0;
  #pragma unroll
  for (int c = 0; c < 4; ++c){
    #pragma unroll
    for (int e = 0; e < 4; ++e){
      float a = (e==0)?av[c].x:(e==1)?av[c].y:(e==2)?av[c].z:av[c].w;
      bool on = a > 0.5f;
      unsigned long long m = __ballot(on);
      int pos = base + __popcll(m & lmask);
      if (on && pos < 128) idxw[wave][pos] = (c * 64 + lane) * 4 + e;
      base += __popcll(m);
    }
  }
  int M = base;                                  // wave-uniform

  const float* kbh = kb + ((size_t)b << 10) * DIMV + wave * 64;
  const float4* qv = (const float4*)qsh[wave];
  const float scale = 0.05103103630798288f;      // 1/sqrt(384)
  float* ob = obuf[wave];
  float* orow = out + (size_t)r * (NHEAD * NSEQ) + wave * NSEQ;

  if (M <= 128){
    // ---- fast path: 1-2 indices per lane, all in registers ----
    float z0 = -1e30f, z1 = -1e30f;
    int  id0 = 0, id1 = 0;
    bool a0 = lane < M;
    bool a1 = false;
    if (a0){
      id0 = idxw[wave][lane];
      z0 = dot64((const float4*)(kbh + (size_t)id0 * DIMV), qv) * scale;
    }
    if (M > 64){
      a1 = (lane + 64) < M;
      if (a1){
        id1 = idxw[wave][lane + 64];
        z1 = dot64((const float4*)(kbh + (size_t)id1 * DIMV), qv) * scale;
      }
    }
    // Michelot: tau fixed point of S={z>tau}, tau=(sum_S-1)/|S|
    float s = (a0 ? z0 : 0.f) + (a1 ? z1 : 0.f);
    float n = (a0 ? 1.f : 0.f) + (a1 ? 1.f : 0.f);
    red2(s, n);
    float tau = (s - 1.f) / n;
    float prevn = n;
    #pragma unroll 1
    for (int it = 0; it < 32; ++it){
      bool i0 = a0 && z0 > tau, i1 = a1 && z1 > tau;
      s = (i0 ? z0 : 0.f) + (i1 ? z1 : 0.f);
      n = (i0 ? 1.f : 0.f) + (i1 ? 1.f : 0.f);
      red2(s, n);
      if (n == prevn) break;                     // support stable -> tau exact
      tau = (s - 1.f) / n;
      prevn = n;
    }
    // stage output row in LDS (same-wave ds ordering), write coalesced
    float4 zf = make_float4(0.f, 0.f, 0.f, 0.f);
    #pragma unroll
    for (int u = 0; u < 4; ++u) ((float4*)ob)[u * 64 + lane] = zf;
    if (a0){ float p = z0 - tau; if (p > 0.f) ob[id0] = p; }
    if (a1){ float p = z1 - tau; if (p > 0.f) ob[id1] = p; }
    #pragma unroll
    for (int u = 0; u < 4; ++u)
      ((float4*)orow)[u * 64 + lane] = ((const float4*)ob)[u * 64 + lane];
  } else {
    // ---- generic fallback (M>128, ~never): obuf holds compacted z ----
    int b2 = 0;
    #pragma unroll
    for (int c = 0; c < 4; ++c){
      #pragma unroll
      for (int e = 0; e < 4; ++e){
        float a = (e==0)?av[c].x:(e==1)?av[c].y:(e==2)?av[c].z:av[c].w;
        bool on = a > 0.5f;
        unsigned long long m = __ballot(on);
        int pre = __popcll(m & lmask);
        if (on){
          int idx = (c * 64 + lane) * 4 + e;
          ob[b2 + pre] = dot64((const float4*)(kbh + (size_t)idx * DIMV), qv) * scale;
        }
        b2 += __popcll(m);
      }
    }
    float s = 0.f, n = 0.f;
    for (int jj = lane; jj < M; jj += 64){ s += ob[jj]; n += 1.f; }
    red2(s, n);
    float tau = (s - 1.f) / n;
    float prevn = n;
    #pragma unroll 1
    for (int it = 0; it < 64; ++it){
      s = 0.f; n = 0.f;
      for (int jj = lane; jj < M; jj += 64){
        float z = ob[jj];
        if (z > tau){ s += z; n += 1.f; }
      }
      red2(s, n);
      if (n == prevn) break;
      tau = (s - 1.f) / n;
      prevn = n;
    }
    float4 zf = make_float4(0.f, 0.f, 0.f, 0.f);
    #pragma unroll
    for (int u = 0; u < 4; ++u) ((float4*)orow)[u * 64 + lane] = zf;
    asm volatile("s_waitcnt vmcnt(0)" ::: "memory");
    b2 = 0;
    #pragma unroll
    for (int c = 0; c < 4; ++c){
      #pragma unroll
      for (int e = 0; e < 4; ++e){
        float a = (e==0)?av[c].x:(e==1)?av[c].y:(e==2)?av[c].z:av[c].w;
        bool on = a > 0.5f;
        unsigned long long m = __ballot(on);
        int pre = __popcll(m & lmask);
        if (on){
          float p = ob[b2 + pre] - tau;
          if (p > 0.f) orow[(c * 64 + lane) * 4 + e] = p;
        }
        b2 += __popcll(m);
      }
    }
  }
}

extern "C" void kernel_launch(void* const* d_in, const int* in_sizes, int n_in,
                              void* d_out, int out_size, void* d_ws, size_t ws_size,
                              hipStream_t stream) {
  const float* Q  = (const float*)d_in[0];
  const float* V  = (const float*)d_in[1];
  const float* A  = (const float*)d_in[2];
  const float* WQ = (const float*)d_in[3];
  const float* bQ = (const float*)d_in[4];
  const float* WK = (const float*)d_in[5];
  const float* bK = (const float*)d_in[6];
  float* out = (float*)d_out;

  char* ws = (char*)d_ws;
  const size_t QK_BYTES = (size_t)8192 * 384 * 4;
  float* qbuf = (float*)ws;
  float* kbuf = (float*)(ws + QK_BYTES);
  unsigned short* wqt = (unsigned short*)(ws + 2 * QK_BYTES);
  unsigned short* wkt = wqt + 98304;
  (void)in_sizes; (void)n_in; (void)out_size; (void)ws_size;

  conv_w_kernel<<<768, 256, 0, stream>>>(WQ, WK, wqt, wkt);
  proj_kernel<<<dim3(128, 4), 256, 0, stream>>>(Q, wqt, bQ, qbuf);
  proj_kernel<<<dim3(128, 4), 256, 0, stream>>>(V, wkt, bK, kbuf);
  attn_kernel<<<8192, 384, 0, stream>>>(qbuf, kbuf, A, out);
}

// Round 4
// 159.743 us; speedup vs baseline: 2.3625x; 1.3256x over previous
//
#include <hip/hip_runtime.h>
#include <hip/hip_bf16.h>
#include <stdint.h>

#define DIMK 256
#define DIMV 384
#define NSEQ 1024
#define NHEAD 6
#define IDXCAP 256

typedef __attribute__((ext_vector_type(8))) short short8;
typedef __attribute__((ext_vector_type(4))) float floatx4;

__device__ __forceinline__ unsigned short f2b(float f){
  unsigned int x = __float_as_uint(f);
  return (unsigned short)((x + 0x7fffu + ((x >> 16) & 1u)) >> 16);
}
__device__ __forceinline__ unsigned int pack2(float a, float b){
  return (unsigned int)f2b(a) | ((unsigned int)f2b(b) << 16);
}
__device__ __forceinline__ float blo(unsigned int u){ return __uint_as_float(u << 16); }
__device__ __forceinline__ float bhi(unsigned int u){ return __uint_as_float(u & 0xffff0000u); }

// transpose + convert: W [256][384] f32 -> Wt [384][256] bf16 (both weights)
__global__ void conv_w_kernel(const float* __restrict__ WQ, const float* __restrict__ WK,
                              unsigned short* __restrict__ wqt, unsigned short* __restrict__ wkt){
  int i = blockIdx.x * 256 + threadIdx.x;
  const float* W; unsigned short* O; int idx;
  if (i < 98304){ W = WQ; O = wqt; idx = i; }
  else          { W = WK; O = wkt; idx = i - 98304; }
  int n = idx >> 8;
  int k = idx & 255;
  O[idx] = f2b(W[(size_t)k * 384 + n]);
}

// A-row ballot compaction: one wave per row -> u16 idx list (cap 256) + count.
__global__ __launch_bounds__(256) void compact_kernel(const float* __restrict__ A,
    unsigned short* __restrict__ idxb, int* __restrict__ Mb){
  int r = blockIdx.x * 4 + (threadIdx.x >> 6);
  int lane = threadIdx.x & 63;
  const float4* arow = (const float4*)(A + (size_t)r * NSEQ);
  float4 av[4];
  #pragma unroll
  for (int c = 0; c < 4; ++c) av[c] = arow[c * 64 + lane];
  unsigned long long lmask = (1ull << lane) - 1ull;
  unsigned short* row = idxb + (size_t)r * IDXCAP;
  int base = 0;
  #pragma unroll
  for (int c = 0; c < 4; ++c){
    #pragma unroll
    for (int e = 0; e < 4; ++e){
      float a = (e==0)?av[c].x:(e==1)?av[c].y:(e==2)?av[c].z:av[c].w;
      bool on = a > 0.5f;
      unsigned long long m = __ballot(on);
      int pos = base + __popcll(m & lmask);
      if (on && pos < IDXCAP) row[pos] = (unsigned short)((c * 64 + lane) * 4 + e);
      base += __popcll(m);
    }
  }
  for (int j = base + lane; j < 128; j += 64) row[j] = 0;   // fast path loads [0,128) unconditionally
  if (lane == 0) Mb[r] = base;
}

// Y = bf16(X[8192][256]) @ bf16(W)[256][384] + bias, written HEAD-MAJOR:
// dst = ((b*6+h)*1024 + n)*64 + d.  BF16OUT: 0 -> f32 (q), 1 -> bf16 (k).
template<int BF16OUT>
__global__ __launch_bounds__(256) void proj_kernel(const float* __restrict__ X,
    const unsigned short* __restrict__ Wt, const float* __restrict__ bias,
    void* __restrict__ Yv)
{
  __shared__ uint4 lA[512];
  __shared__ uint4 lB[864];
  int t = threadIdx.x;
  int lane = t & 63, wave = t >> 6;
  int wm = wave >> 1, wn = wave & 1;
  int rb = blockIdx.x * 64;
  int nb = blockIdx.y * 96;
  floatx4 acc[2][3];
  #pragma unroll
  for (int mi = 0; mi < 2; ++mi)
    #pragma unroll
    for (int ni = 0; ni < 3; ++ni) acc[mi][ni] = (floatx4){0.f, 0.f, 0.f, 0.f};

  for (int it = 0; it < 4; ++it){
    int k0 = it * 64;
    #pragma unroll
    for (int i = 0; i < 2; ++i){
      int c = t + i * 256;
      int kc = c >> 6, row = c & 63;
      const float* src = X + (size_t)(rb + row) * DIMK + k0 + kc * 8;
      float4 f0 = *(const float4*)src;
      float4 f1 = *(const float4*)(src + 4);
      uint4 w;
      w.x = pack2(f0.x, f0.y); w.y = pack2(f0.z, f0.w);
      w.z = pack2(f1.x, f1.y); w.w = pack2(f1.z, f1.w);
      lA[c] = w;
    }
    #pragma unroll
    for (int i = 0; i < 3; ++i){
      int c = t + i * 256;
      int n = c >> 3, kc = c & 7;
      uint4 v = *(const uint4*)(Wt + (size_t)(nb + n) * DIMK + k0 + kc * 8);
      lB[n * 9 + kc] = v;
    }
    __syncthreads();
    #pragma unroll
    for (int kk = 0; kk < 2; ++kk){
      int kc  = kk * 4 + (lane >> 4);
      int r16 = lane & 15;
      short8 af[2], bf[3];
      #pragma unroll
      for (int mi = 0; mi < 2; ++mi)
        af[mi] = *(const short8*)&lA[kc * 64 + wm * 32 + mi * 16 + r16];
      #pragma unroll
      for (int ni = 0; ni < 3; ++ni)
        bf[ni] = *(const short8*)&lB[(wn * 48 + ni * 16 + r16) * 9 + kc];
      #pragma unroll
      for (int mi = 0; mi < 2; ++mi)
        #pragma unroll
        for (int ni = 0; ni < 3; ++ni)
          acc[mi][ni] = __builtin_amdgcn_mfma_f32_16x16x32_bf16(af[mi], bf[ni], acc[mi][ni], 0, 0, 0);
    }
    __syncthreads();
  }
  int r16 = lane & 15, rq = lane >> 4;
  #pragma unroll
  for (int ni = 0; ni < 3; ++ni){
    int col = nb + wn * 48 + ni * 16 + r16;
    float bv = bias[col];
    int h = col >> 6, d = col & 63;
    #pragma unroll
    for (int mi = 0; mi < 2; ++mi){
      #pragma unroll
      for (int q = 0; q < 4; ++q){
        int row = rb + wm * 32 + mi * 16 + rq * 4 + q;
        int bb = row >> 10, n = row & 1023;
        size_t dst = ((size_t)(bb * NHEAD + h) * NSEQ + n) * 64 + d;
        float v = acc[mi][ni][q] + bv;
        if (BF16OUT) ((unsigned short*)Yv)[dst] = f2b(v);
        else         ((float*)Yv)[dst] = v;
      }
    }
  }
}

// 64-dim dot: k row bf16 (128B), q row f32 in LDS (broadcast reads)
__device__ __forceinline__ float dotqk(const unsigned short* __restrict__ krow,
                                       const float* __restrict__ qrow){
  const uint4* kp = (const uint4*)krow;
  float z = 0.f;
  #pragma unroll
  for (int c = 0; c < 8; ++c){
    uint4 k = kp[c];
    const float4* qp = (const float4*)(qrow + c * 8);
    float4 qa = qp[0], qb = qp[1];
    z += blo(k.x)*qa.x + bhi(k.x)*qa.y + blo(k.y)*qa.z + bhi(k.y)*qa.w
       + blo(k.z)*qb.x + bhi(k.z)*qb.y + blo(k.w)*qb.z + bhi(k.w)*qb.w;
  }
  return z;
}

__device__ __forceinline__ void red2(float& s, float& n){
  #pragma unroll
  for (int o = 1; o < 64; o <<= 1){ s += __shfl_xor(s, o); n += __shfl_xor(n, o); }
}
__device__ __forceinline__ void red4(float& a, float& b, float& c, float& d){
  #pragma unroll
  for (int o = 1; o < 64; o <<= 1){
    a += __shfl_xor(a, o); b += __shfl_xor(b, o);
    c += __shfl_xor(c, o); d += __shfl_xor(d, o);
  }
}

// One workgroup per row-PAIR; 6 independent waves = 1 per head; no barriers.
// Per wave: two rows' {M, idx, q} loads issued together, two interleaved
// dot+Michelot chains, LDS-staged coalesced output.
__global__ __launch_bounds__(384) void attn_kernel(const float* __restrict__ qb2,
    const unsigned short* __restrict__ kb2, const unsigned short* __restrict__ idxb,
    const int* __restrict__ Mb, float* __restrict__ out)
{
  __shared__ float obuf[NHEAD][NSEQ];
  __shared__ float qsh[NHEAD][2][64];

  int bid = blockIdx.x;
  int p = ((bid & 7) << 9) | (bid >> 3);       // XCD x owns batch x (4096 pairs)
  int r0 = p * 2, r1 = r0 + 1;
  int b = r0 >> 10;
  int t = threadIdx.x;
  int lane = t & 63, w = t >> 6;

  size_t headoff = (size_t)(b * NHEAD + w) * NSEQ;
  int n0 = r0 & 1023;
  qsh[w][0][lane] = qb2[(headoff + n0) * 64 + lane];
  qsh[w][1][lane] = qb2[(headoff + n0 + 1) * 64 + lane];

  int M0 = Mb[r0], M1 = Mb[r1];
  const unsigned short* i0p = idxb + (size_t)r0 * IDXCAP;
  const unsigned short* i1p = idxb + (size_t)r1 * IDXCAP;
  const unsigned short* kh = kb2 + headoff * 64;
  const float scale = 0.05103103630798288f;    // 1/sqrt(384)
  float* ob = obuf[w];
  float* orow0 = out + (size_t)r0 * (NHEAD * NSEQ) + w * NSEQ;
  float* orow1 = out + (size_t)r1 * (NHEAD * NSEQ) + w * NSEQ;
  float4 zf = make_float4(0.f, 0.f, 0.f, 0.f);

  if (M0 <= 128 && M1 <= 128){
    // ---- fast path: everything in registers, 2 rows interleaved ----
    int idA0 = i0p[lane];
    int idB0 = i1p[lane];
    bool aA0 = lane < M0, aB0 = lane < M1;
    float zA0 = dotqk(kh + (size_t)idA0 * 64, qsh[w][0]) * scale;
    float zB0 = dotqk(kh + (size_t)idB0 * 64, qsh[w][1]) * scale;
    float zA1 = 0.f, zB1 = 0.f;
    int idA1 = 0, idB1 = 0;
    bool aA1 = false, aB1 = false;
    if (M0 > 64){
      idA1 = i0p[64 + lane];
      aA1 = (64 + lane) < M0;
      zA1 = dotqk(kh + (size_t)idA1 * 64, qsh[w][0]) * scale;
    }
    if (M1 > 64){
      idB1 = i1p[64 + lane];
      aB1 = (64 + lane) < M1;
      zB1 = dotqk(kh + (size_t)idB1 * 64, qsh[w][1]) * scale;
    }
    // Michelot fixed point, both rows together
    float s0 = (aA0 ? zA0 : 0.f) + (aA1 ? zA1 : 0.f);
    float c0 = (aA0 ? 1.f : 0.f) + (aA1 ? 1.f : 0.f);
    float s1 = (aB0 ? zB0 : 0.f) + (aB1 ? zB1 : 0.f);
    float c1 = (aB0 ? 1.f : 0.f) + (aB1 ? 1.f : 0.f);
    red4(s0, c0, s1, c1);
    float tau0 = (s0 - 1.f) / c0, tau1 = (s1 - 1.f) / c1;
    float p0 = c0, p1 = c1;
    #pragma unroll 1
    for (int it = 0; it < 32; ++it){
      bool iA0 = aA0 && zA0 > tau0, iA1 = aA1 && zA1 > tau0;
      bool iB0 = aB0 && zB0 > tau1, iB1 = aB1 && zB1 > tau1;
      s0 = (iA0 ? zA0 : 0.f) + (iA1 ? zA1 : 0.f);
      c0 = (iA0 ? 1.f : 0.f) + (iA1 ? 1.f : 0.f);
      s1 = (iB0 ? zB0 : 0.f) + (iB1 ? zB1 : 0.f);
      c1 = (iB0 ? 1.f : 0.f) + (iB1 ? 1.f : 0.f);
      red4(s0, c0, s1, c1);
      bool stable = (c0 == p0) && (c1 == p1);
      tau0 = (s0 - 1.f) / c0; tau1 = (s1 - 1.f) / c1;
      p0 = c0; p1 = c1;
      if (stable) break;
    }
    // row0 out via LDS staging
    #pragma unroll
    for (int u = 0; u < 4; ++u) ((float4*)ob)[u * 64 + lane] = zf;
    if (aA0){ float pp = zA0 - tau0; if (pp > 0.f) ob[idA0] = pp; }
    if (aA1){ float pp = zA1 - tau0; if (pp > 0.f) ob[idA1] = pp; }
    #pragma unroll
    for (int u = 0; u < 4; ++u)
      ((float4*)orow0)[u * 64 + lane] = ((const float4*)ob)[u * 64 + lane];
    // row1 out (reuse staging; same-wave LDS ordering)
    #pragma unroll
    for (int u = 0; u < 4; ++u) ((float4*)ob)[u * 64 + lane] = zf;
    if (aB0){ float pp = zB0 - tau1; if (pp > 0.f) ob[idB0] = pp; }
    if (aB1){ float pp = zB1 - tau1; if (pp > 0.f) ob[idB1] = pp; }
    #pragma unroll
    for (int u = 0; u < 4; ++u)
      ((float4*)orow1)[u * 64 + lane] = ((const float4*)ob)[u * 64 + lane];
  } else {
    // ---- generic fallback (M>128, ~never): z staged in obuf, M<=IDXCAP ----
    #pragma unroll 1
    for (int rr = 0; rr < 2; ++rr){
      int M = rr ? M1 : M0;
      const unsigned short* ip = rr ? i1p : i0p;
      const float* qr = qsh[w][rr];
      float* orow = rr ? orow1 : orow0;
      #pragma unroll 1
      for (int j0 = 0; j0 < M; j0 += 64){
        int jj = j0 + lane;
        if (jj < M){
          int idx = ip[jj];
          ob[jj] = dotqk(kh + (size_t)idx * 64, qr) * scale;
        }
      }
      float s = 0.f, c = 0.f;
      for (int jj = lane; jj < M; jj += 64){ s += ob[jj]; c += 1.f; }
      red2(s, c);
      float tau = (s - 1.f) / c, pn = c;
      #pragma unroll 1
      for (int it = 0; it < 64; ++it){
        s = 0.f; c = 0.f;
        for (int jj = lane; jj < M; jj += 64){
          float z = ob[jj];
          if (z > tau){ s += z; c += 1.f; }
        }
        red2(s, c);
        if (c == pn) break;
        tau = (s - 1.f) / c; pn = c;
      }
      #pragma unroll
      for (int u = 0; u < 4; ++u) ((float4*)orow)[u * 64 + lane] = zf;
      asm volatile("s_waitcnt vmcnt(0)" ::: "memory");
      for (int jj = lane; jj < M; jj += 64){
        float pp = ob[jj] - tau;
        int idx = ip[jj];
        if (pp > 0.f) orow[idx] = pp;
      }
    }
  }
}

extern "C" void kernel_launch(void* const* d_in, const int* in_sizes, int n_in,
                              void* d_out, int out_size, void* d_ws, size_t ws_size,
                              hipStream_t stream) {
  const float* Q  = (const float*)d_in[0];
  const float* V  = (const float*)d_in[1];
  const float* A  = (const float*)d_in[2];
  const float* WQ = (const float*)d_in[3];
  const float* bQ = (const float*)d_in[4];
  const float* WK = (const float*)d_in[5];
  const float* bK = (const float*)d_in[6];
  float* out = (float*)d_out;

  char* ws = (char*)d_ws;
  float*          qb2  = (float*)ws;                                   // 12.58 MB f32 head-major
  unsigned short* kb2  = (unsigned short*)(ws + (size_t)12582912);     //  6.29 MB bf16 head-major
  unsigned short* wqt  = (unsigned short*)(ws + (size_t)18874368);     //  0.20 MB
  unsigned short* wkt  = wqt + 98304;                                  //  0.20 MB
  unsigned short* idxb = (unsigned short*)(ws + (size_t)19267584);     //  4.19 MB
  int*            Mb   = (int*)(ws + (size_t)23461888);                //  32 KB
  (void)in_sizes; (void)n_in; (void)out_size; (void)ws_size;

  conv_w_kernel<<<768, 256, 0, stream>>>(WQ, WK, wqt, wkt);
  compact_kernel<<<2048, 256, 0, stream>>>(A, idxb, Mb);
  proj_kernel<0><<<dim3(128, 4), 256, 0, stream>>>(Q, wqt, bQ, (void*)qb2);
  proj_kernel<1><<<dim3(128, 4), 256, 0, stream>>>(V, wkt, bK, (void*)kb2);
  attn_kernel<<<4096, 384, 0, stream>>>(qb2, kb2, idxb, Mb, out);
}

// Round 6
// 139.973 us; speedup vs baseline: 2.6962x; 1.1412x over previous
//
#include <hip/hip_runtime.h>
#include <hip/hip_bf16.h>
#include <stdint.h>

#define DIMK 256
#define DIMV 384
#define NSEQ 1024
#define NHEAD 6
#define IDXCAP 256

typedef __attribute__((ext_vector_type(8))) short short8;
typedef __attribute__((ext_vector_type(4))) float floatx4;

__device__ __forceinline__ unsigned short f2b(float f){
  unsigned int x = __float_as_uint(f);
  return (unsigned short)((x + 0x7fffu + ((x >> 16) & 1u)) >> 16);
}
__device__ __forceinline__ unsigned int pack2(float a, float b){
  return (unsigned int)f2b(a) | ((unsigned int)f2b(b) << 16);
}
__device__ __forceinline__ float blo(unsigned int u){ return __uint_as_float(u << 16); }
__device__ __forceinline__ float bhi(unsigned int u){ return __uint_as_float(u & 0xffff0000u); }

// transpose + convert: W [256][384] f32 -> Wt [384][256] bf16 (both weights)
__global__ void conv_w_kernel(const float* __restrict__ WQ, const float* __restrict__ WK,
                              unsigned short* __restrict__ wqt, unsigned short* __restrict__ wkt){
  int i = blockIdx.x * 256 + threadIdx.x;
  const float* W; unsigned short* O; int idx;
  if (i < 98304){ W = WQ; O = wqt; idx = i; }
  else          { W = WK; O = wkt; idx = i - 98304; }
  int n = idx >> 8;
  int k = idx & 255;
  O[idx] = f2b(W[(size_t)k * 384 + n]);
}

// A-row ballot compaction: one wave per row -> u16 idx list (cap 256) + count.
__global__ __launch_bounds__(256) void compact_kernel(const float* __restrict__ A,
    unsigned short* __restrict__ idxb, int* __restrict__ Mb){
  int r = blockIdx.x * 4 + (threadIdx.x >> 6);
  int lane = threadIdx.x & 63;
  const float4* arow = (const float4*)(A + (size_t)r * NSEQ);
  float4 av[4];
  #pragma unroll
  for (int c = 0; c < 4; ++c) av[c] = arow[c * 64 + lane];
  unsigned long long lmask = (1ull << lane) - 1ull;
  unsigned short* row = idxb + (size_t)r * IDXCAP;
  int base = 0;
  #pragma unroll
  for (int c = 0; c < 4; ++c){
    #pragma unroll
    for (int e = 0; e < 4; ++e){
      float a = (e==0)?av[c].x:(e==1)?av[c].y:(e==2)?av[c].z:av[c].w;
      bool on = a > 0.5f;
      unsigned long long m = __ballot(on);
      int pos = base + __popcll(m & lmask);
      if (on && pos < IDXCAP) row[pos] = (unsigned short)((c * 64 + lane) * 4 + e);
      base += __popcll(m);
    }
  }
  for (int j = base + lane; j < 128; j += 64) row[j] = 0;   // fast path reads [0,128)
  if (lane == 0) Mb[r] = base;
}

// Y = bf16(X[8192][256]) @ bf16(W)[256][384] + bias, written HEAD-MAJOR:
// dst = ((b*6+h)*1024 + n)*64 + d.  BF16OUT: 0 -> f32 (q), 1 -> bf16 (k).
template<int BF16OUT>
__global__ __launch_bounds__(256) void proj_kernel(const float* __restrict__ X,
    const unsigned short* __restrict__ Wt, const float* __restrict__ bias,
    void* __restrict__ Yv)
{
  __shared__ uint4 lA[512];
  __shared__ uint4 lB[864];
  int t = threadIdx.x;
  int lane = t & 63, wave = t >> 6;
  int wm = wave >> 1, wn = wave & 1;
  int rb = blockIdx.x * 64;
  int nb = blockIdx.y * 96;
  floatx4 acc[2][3];
  #pragma unroll
  for (int mi = 0; mi < 2; ++mi)
    #pragma unroll
    for (int ni = 0; ni < 3; ++ni) acc[mi][ni] = (floatx4){0.f, 0.f, 0.f, 0.f};

  for (int it = 0; it < 4; ++it){
    int k0 = it * 64;
    #pragma unroll
    for (int i = 0; i < 2; ++i){
      int c = t + i * 256;
      int kc = c >> 6, row = c & 63;
      const float* src = X + (size_t)(rb + row) * DIMK + k0 + kc * 8;
      float4 f0 = *(const float4*)src;
      float4 f1 = *(const float4*)(src + 4);
      uint4 w;
      w.x = pack2(f0.x, f0.y); w.y = pack2(f0.z, f0.w);
      w.z = pack2(f1.x, f1.y); w.w = pack2(f1.z, f1.w);
      lA[c] = w;
    }
    #pragma unroll
    for (int i = 0; i < 3; ++i){
      int c = t + i * 256;
      int n = c >> 3, kc = c & 7;
      uint4 v = *(const uint4*)(Wt + (size_t)(nb + n) * DIMK + k0 + kc * 8);
      lB[n * 9 + kc] = v;
    }
    __syncthreads();
    #pragma unroll
    for (int kk = 0; kk < 2; ++kk){
      int kc  = kk * 4 + (lane >> 4);
      int r16 = lane & 15;
      short8 af[2], bf[3];
      #pragma unroll
      for (int mi = 0; mi < 2; ++mi)
        af[mi] = *(const short8*)&lA[kc * 64 + wm * 32 + mi * 16 + r16];
      #pragma unroll
      for (int ni = 0; ni < 3; ++ni)
        bf[ni] = *(const short8*)&lB[(wn * 48 + ni * 16 + r16) * 9 + kc];
      #pragma unroll
      for (int mi = 0; mi < 2; ++mi)
        #pragma unroll
        for (int ni = 0; ni < 3; ++ni)
          acc[mi][ni] = __builtin_amdgcn_mfma_f32_16x16x32_bf16(af[mi], bf[ni], acc[mi][ni], 0, 0, 0);
    }
    __syncthreads();
  }
  int r16 = lane & 15, rq = lane >> 4;
  #pragma unroll
  for (int ni = 0; ni < 3; ++ni){
    int col = nb + wn * 48 + ni * 16 + r16;
    float bv = bias[col];
    int h = col >> 6, d = col & 63;
    #pragma unroll
    for (int mi = 0; mi < 2; ++mi){
      #pragma unroll
      for (int q = 0; q < 4; ++q){
        int row = rb + wm * 32 + mi * 16 + rq * 4 + q;
        int bb = row >> 10, n = row & 1023;
        size_t dst = ((size_t)(bb * NHEAD + h) * NSEQ + n) * 64 + d;
        float v = acc[mi][ni][q] + bv;
        if (BF16OUT) ((unsigned short*)Yv)[dst] = f2b(v);
        else         ((float*)Yv)[dst] = v;
      }
    }
  }
}

// 64-dim dot: k row bf16 (128B), q row f32 in LDS (uniform-address broadcast)
__device__ __forceinline__ float dotqk(const unsigned short* __restrict__ krow,
                                       const float* __restrict__ qrow){
  const uint4* kp = (const uint4*)krow;
  float z = 0.f;
  #pragma unroll
  for (int c = 0; c < 8; ++c){
    uint4 k = kp[c];
    const float4* qp = (const float4*)(qrow + c * 8);
    float4 qa = qp[0], qb = qp[1];
    z += blo(k.x)*qa.x + bhi(k.x)*qa.y + blo(k.y)*qa.z + bhi(k.y)*qa.w
       + blo(k.z)*qb.x + bhi(k.z)*qb.y + blo(k.w)*qb.z + bhi(k.w)*qb.w;
  }
  return z;
}

__device__ __forceinline__ void red2(float& s, float& n){
  #pragma unroll
  for (int o = 1; o < 64; o <<= 1){ s += __shfl_xor(s, o); n += __shfl_xor(n, o); }
}
__device__ __forceinline__ void red4(float& a, float& b, float& c, float& d){
  #pragma unroll
  for (int o = 1; o < 64; o <<= 1){
    a += __shfl_xor(a, o); b += __shfl_xor(b, o);
    c += __shfl_xor(c, o); d += __shfl_xor(d, o);
  }
}

// ONE WAVE per workgroup, one (row-pair, head) each: wave-granular scheduling,
// ~16 independent waves/CU. No cross-wave coupling, tiny LDS footprint.
__global__ __launch_bounds__(64) void attn_kernel(const float* __restrict__ qb2,
    const unsigned short* __restrict__ kb2, const unsigned short* __restrict__ idxb,
    const int* __restrict__ Mb, float* __restrict__ out)
{
  __shared__ float obuf[2][NSEQ];
  __shared__ float qsh[2][64];

  int bid = blockIdx.x;
  int x = bid & 7;            // batch == XCD
  int u = bid >> 3;           // 0..3071
  int h = u >> 9;             // head 0..5
  int pp = u & 511;           // pair within batch
  int r0 = (x << 10) + (pp << 1), r1 = r0 + 1;
  int lane = threadIdx.x;

  size_t headoff = (size_t)(x * NHEAD + h) * NSEQ;
  int n0 = r0 & 1023;
  qsh[0][lane] = qb2[(headoff + n0) * 64 + lane];
  qsh[1][lane] = qb2[(headoff + n0 + 1) * 64 + lane];

  int M0 = Mb[r0], M1 = Mb[r1];
  const unsigned short* i0p = idxb + (size_t)r0 * IDXCAP;
  const unsigned short* i1p = idxb + (size_t)r1 * IDXCAP;
  const unsigned short* kh = kb2 + headoff * 64;
  const float scale = 0.05103103630798288f;    // 1/sqrt(384)
  float* orow0 = out + (size_t)r0 * (NHEAD * NSEQ) + h * NSEQ;
  float* orow1 = out + (size_t)r1 * (NHEAD * NSEQ) + h * NSEQ;
  float4 zf = make_float4(0.f, 0.f, 0.f, 0.f);

  // pre-zero both staging rows (no downstream dependency until scatter)
  #pragma unroll
  for (int v = 0; v < 4; ++v){
    ((float4*)obuf[0])[v * 64 + lane] = zf;
    ((float4*)obuf[1])[v * 64 + lane] = zf;
  }

  if (M0 <= 128 && M1 <= 128){
    // ---- fast path: 1-2 indices per lane per row, all in registers ----
    int idA0 = i0p[lane];
    int idB0 = i1p[lane];
    bool aA0 = lane < M0, aB0 = lane < M1;
    float zA0 = dotqk(kh + (size_t)idA0 * 64, qsh[0]) * scale;
    float zB0 = dotqk(kh + (size_t)idB0 * 64, qsh[1]) * scale;
    float zA1 = 0.f, zB1 = 0.f;
    int idA1 = 0, idB1 = 0;
    bool aA1 = false, aB1 = false;
    if (M0 > 64){
      idA1 = i0p[64 + lane];
      aA1 = (64 + lane) < M0;
      zA1 = dotqk(kh + (size_t)idA1 * 64, qsh[0]) * scale;
    }
    if (M1 > 64){
      idB1 = i1p[64 + lane];
      aB1 = (64 + lane) < M1;
      zB1 = dotqk(kh + (size_t)idB1 * 64, qsh[1]) * scale;
    }
    // Michelot fixed point: tau = (sum_{z>tau} z - 1)/|{z>tau}|
    float s0 = (aA0 ? zA0 : 0.f) + (aA1 ? zA1 : 0.f);
    float c0 = (aA0 ? 1.f : 0.f) + (aA1 ? 1.f : 0.f);
    float s1 = (aB0 ? zB0 : 0.f) + (aB1 ? zB1 : 0.f);
    float c1 = (aB0 ? 1.f : 0.f) + (aB1 ? 1.f : 0.f);
    red4(s0, c0, s1, c1);
    float tau0 = (s0 - 1.f) / c0, tau1 = (s1 - 1.f) / c1;
    float p0 = c0, p1 = c1;
    #pragma unroll 1
    for (int it = 0; it < 32; ++it){
      bool iA0 = aA0 && zA0 > tau0, iA1 = aA1 && zA1 > tau0;
      bool iB0 = aB0 && zB0 > tau1, iB1 = aB1 && zB1 > tau1;
      s0 = (iA0 ? zA0 : 0.f) + (iA1 ? zA1 : 0.f);
      c0 = (iA0 ? 1.f : 0.f) + (iA1 ? 1.f : 0.f);
      s1 = (iB0 ? zB0 : 0.f) + (iB1 ? zB1 : 0.f);
      c1 = (iB0 ? 1.f : 0.f) + (iB1 ? 1.f : 0.f);
      red4(s0, c0, s1, c1);
      bool stable = (c0 == p0) && (c1 == p1);
      tau0 = (s0 - 1.f) / c0; tau1 = (s1 - 1.f) / c1;
      p0 = c0; p1 = c1;
      if (stable) break;
    }
    // scatter both rows, then stream out (nontemporal: write-once data)
    if (aA0){ float q = zA0 - tau0; if (q > 0.f) obuf[0][idA0] = q; }
    if (aA1){ float q = zA1 - tau0; if (q > 0.f) obuf[0][idA1] = q; }
    if (aB0){ float q = zB0 - tau1; if (q > 0.f) obuf[1][idB0] = q; }
    if (aB1){ float q = zB1 - tau1; if (q > 0.f) obuf[1][idB1] = q; }
    #pragma unroll
    for (int v = 0; v < 4; ++v){
      floatx4 w0 = ((const floatx4*)obuf[0])[v * 64 + lane];
      floatx4 w1 = ((const floatx4*)obuf[1])[v * 64 + lane];
      __builtin_nontemporal_store(w0, &((floatx4*)orow0)[v * 64 + lane]);
      __builtin_nontemporal_store(w1, &((floatx4*)orow1)[v * 64 + lane]);
    }
  } else {
    // ---- generic fallback (M>128, ~never): z staged in obuf row ----
    #pragma unroll 1
    for (int rr = 0; rr < 2; ++rr){
      int M = rr ? M1 : M0;
      const unsigned short* ip = rr ? i1p : i0p;
      const float* qr = qsh[rr];
      float* orow = rr ? orow1 : orow0;
      float* ob = obuf[0];
      #pragma unroll 1
      for (int j0 = 0; j0 < M; j0 += 64){
        int jj = j0 + lane;
        if (jj < M){
          int idx = ip[jj];
          ob[jj] = dotqk(kh + (size_t)idx * 64, qr) * scale;
        }
      }
      float s = 0.f, c = 0.f;
      for (int jj = lane; jj < M; jj += 64){ s += ob[jj]; c += 1.f; }
      red2(s, c);
      float tau = (s - 1.f) / c, pn = c;
      #pragma unroll 1
      for (int it = 0; it < 64; ++it){
        s = 0.f; c = 0.f;
        for (int jj = lane; jj < M; jj += 64){
          float z = ob[jj];
          if (z > tau){ s += z; c += 1.f; }
        }
        red2(s, c);
        if (c == pn) break;
        tau = (s - 1.f) / c; pn = c;
      }
      #pragma unroll
      for (int v = 0; v < 4; ++v) ((float4*)orow)[v * 64 + lane] = zf;
      asm volatile("s_waitcnt vmcnt(0)" ::: "memory");
      for (int jj = lane; jj < M; jj += 64){
        float q = ob[jj] - tau;
        int idx = ip[jj];
        if (q > 0.f) orow[idx] = q;
      }
    }
  }
}

extern "C" void kernel_launch(void* const* d_in, const int* in_sizes, int n_in,
                              void* d_out, int out_size, void* d_ws, size_t ws_size,
                              hipStream_t stream) {
  const float* Q  = (const float*)d_in[0];
  const float* V  = (const float*)d_in[1];
  const float* A  = (const float*)d_in[2];
  const float* WQ = (const float*)d_in[3];
  const float* bQ = (const float*)d_in[4];
  const float* WK = (const float*)d_in[5];
  const float* bK = (const float*)d_in[6];
  float* out = (float*)d_out;

  char* ws = (char*)d_ws;
  float*          qb2  = (float*)ws;                                   // 12.58 MB f32 head-major
  unsigned short* kb2  = (unsigned short*)(ws + (size_t)12582912);     //  6.29 MB bf16 head-major
  unsigned short* wqt  = (unsigned short*)(ws + (size_t)18874368);
  unsigned short* wkt  = wqt + 98304;
  unsigned short* idxb = (unsigned short*)(ws + (size_t)19267584);     //  4.19 MB
  int*            Mb   = (int*)(ws + (size_t)23461888);                //  32 KB
  (void)in_sizes; (void)n_in; (void)out_size; (void)ws_size;

  conv_w_kernel<<<768, 256, 0, stream>>>(WQ, WK, wqt, wkt);
  compact_kernel<<<2048, 256, 0, stream>>>(A, idxb, Mb);
  proj_kernel<0><<<dim3(128, 4), 256, 0, stream>>>(Q, wqt, bQ, (void*)qb2);
  proj_kernel<1><<<dim3(128, 4), 256, 0, stream>>>(V, wkt, bK, (void*)kb2);
  attn_kernel<<<24576, 64, 0, stream>>>(qb2, kb2, idxb, Mb, out);
}